// Round 2
// baseline (410.990 us; speedup 1.0000x reference)
//
#include <hip/hip_runtime.h>
#include <hip/hip_bf16.h>

#define B_    32
#define C_    512
#define S_    1024
#define G_    32
#define CPG_  16
#define C3_   1536
#define EPS_  1e-5f
#define SCALE_ 0.044194173824159216f   // 1/sqrt(512), folded into K during qkv epilogue

typedef __attribute__((ext_vector_type(4))) float  floatx4;
typedef __attribute__((ext_vector_type(8))) __bf16 bf16x8;

__device__ __forceinline__ float bf2f(unsigned short u) {
    union { unsigned int i; float f; } v; v.i = ((unsigned int)u) << 16; return v.f;
}
__device__ __forceinline__ unsigned short f2bf(float f) {
    union { float f; unsigned int i; } v; v.f = f;
    unsigned int r = v.i + 0x7fffu + ((v.i >> 16) & 1u);
    return (unsigned short)(r >> 16);
}

// direct global->LDS DMA, 16 bytes per lane. LDS dest = wave-uniform base + lane*16.
__device__ __forceinline__ void gl16(const unsigned short* g, unsigned short* l) {
    __builtin_amdgcn_global_load_lds(
        (const __attribute__((address_space(1))) unsigned int*)g,
        (__attribute__((address_space(3))) unsigned int*)l, 16, 0, 0);
}

// ---------------- group-norm stats ----------------
__global__ __launch_bounds__(256) void gn_stats(const float* __restrict__ x,
                                                float2* __restrict__ stats) {
    const size_t base = (size_t)blockIdx.x * (CPG_ * S_);
    const float4* xp = (const float4*)(x + base);
    float s = 0.f, ss = 0.f;
    for (int i = threadIdx.x; i < (CPG_ * S_) / 4; i += 256) {
        float4 v = xp[i];
        s  += v.x + v.y + v.z + v.w;
        ss += v.x * v.x + v.y * v.y + v.z * v.z + v.w * v.w;
    }
    #pragma unroll
    for (int o = 32; o; o >>= 1) { s += __shfl_down(s, o); ss += __shfl_down(ss, o); }
    __shared__ float a1[4], a2[4];
    const int wid = threadIdx.x >> 6, lane = threadIdx.x & 63;
    if (lane == 0) { a1[wid] = s; a2[wid] = ss; }
    __syncthreads();
    if (threadIdx.x == 0) {
        float S  = a1[0] + a1[1] + a1[2] + a1[3];
        float SS = a2[0] + a2[1] + a2[2] + a2[3];
        float mean = S * (1.f / 16384.f);
        float var  = SS * (1.f / 16384.f) - mean * mean;
        stats[blockIdx.x] = make_float2(mean, rsqrtf(var + EPS_));
    }
}

// ---------------- fp32 -> bf16 convert ----------------
__global__ __launch_bounds__(256) void cast_bf16(const float* __restrict__ src,
                                                 unsigned short* __restrict__ dst) {
    int i = (blockIdx.x * 256 + threadIdx.x) * 4;
    float4 v = *(const float4*)(src + i);
    ushort4 o; o.x = f2bf(v.x); o.y = f2bf(v.y); o.z = f2bf(v.z); o.w = f2bf(v.w);
    *(ushort4*)(dst + i) = o;
}

// ---------------- normalized x, transposed to [b][s][c], bf16 ----------------
__global__ __launch_bounds__(256) void xnt_kernel(const float* __restrict__ x,
                                                  const float* __restrict__ gamma,
                                                  const float* __restrict__ beta,
                                                  const float2* __restrict__ stats,
                                                  unsigned short* __restrict__ xnt) {
    const int b = blockIdx.z, c0 = blockIdx.y * 64, s0 = blockIdx.x * 64;
    __shared__ float tile[64][65];
    const float* xb = x + (size_t)b * (C_ * S_);
    const int t = threadIdx.x, tr = t >> 4, tc4 = (t & 15) * 4;
    #pragma unroll
    for (int i = 0; i < 4; i++) {
        int r = tr + i * 16;
        int c = c0 + r;
        float2 mv = stats[b * G_ + (c >> 4)];
        float a  = mv.y * gamma[c];
        float bb = beta[c] - mv.x * a;
        float4 v = *(const float4*)(xb + (size_t)c * S_ + s0 + tc4);
        tile[r][tc4 + 0] = a * v.x + bb;
        tile[r][tc4 + 1] = a * v.y + bb;
        tile[r][tc4 + 2] = a * v.z + bb;
        tile[r][tc4 + 3] = a * v.w + bb;
    }
    __syncthreads();
    unsigned short* xo = xnt + (size_t)b * (S_ * C_);
    #pragma unroll
    for (int i = 0; i < 4; i++) {
        int sr = tr + i * 16;
        ushort4 o4;
        o4.x = f2bf(tile[tc4 + 0][sr]);
        o4.y = f2bf(tile[tc4 + 1][sr]);
        o4.z = f2bf(tile[tc4 + 2][sr]);
        o4.w = f2bf(tile[tc4 + 3][sr]);
        *(ushort4*)(xo + (size_t)(s0 + sr) * C_ + c0 + tc4) = o4;
    }
}

// ================= 256x256 8-phase pipelined MFMA mainloop (BK=64) =================
// (unchanged from R1 — used by qkv and out projections)
template<bool SWAP>
__device__ __forceinline__ void mfma256_loop(const unsigned short* __restrict__ Ag, int lda,
                                             const unsigned short* __restrict__ Bg, int ldb,
                                             int nt, int m0, int n0,
                                             unsigned short* lds, floatx4 (&acc)[8][4]) {
    const int tid  = threadIdx.x;
    const int lane = tid & 63, wave = tid >> 6;
    const int wm = wave >> 2, wn = wave & 3;
    const int lrow = lane & 15, lq = lane >> 4;
    const int cs = lq ^ ((lrow >> 1) & 3);

    int aofs[8], bofs[4];
    #pragma unroll
    for (int i = 0; i < 8; i++) aofs[i] = (wm * 128 + i * 16 + lrow) * 32 + cs * 8;
    #pragma unroll
    for (int j = 0; j < 4; j++) bofs[j] = (wn * 64 + j * 16 + lrow) * 32 + cs * 8;

    const int sr  = tid >> 2;
    const int scs = (tid & 3) ^ ((tid >> 3) & 3);
    const unsigned short* gA = Ag + (size_t)(m0 + sr) * lda + scs * 8;
    const unsigned short* gB = Bg + (size_t)(n0 + sr) * ldb + scs * 8;
    const size_t a128 = (size_t)128 * lda, b128 = (size_t)128 * ldb;
    unsigned short* lwA = lds + wave * 512;
    unsigned short* lwB = lds + 32768 + wave * 512;

#define STAGE_A(t, kh) do { \
    unsigned short* lb_ = lwA + ((t) & 1) * 16384 + (kh) * 8192; \
    const unsigned short* gp_ = gA + (t) * 64 + (kh) * 32; \
    gl16(gp_, lb_); gl16(gp_ + a128, lb_ + 4096); } while (0)
#define STAGE_B(t, kh) do { \
    unsigned short* lb_ = lwB + ((t) & 1) * 16384 + (kh) * 8192; \
    const unsigned short* gp_ = gB + (t) * 64 + (kh) * 32; \
    gl16(gp_, lb_); gl16(gp_ + b128, lb_ + 4096); } while (0)

    STAGE_A(0, 0); STAGE_B(0, 0); STAGE_A(0, 1); STAGE_B(0, 1);
    STAGE_A(1, 0); STAGE_B(1, 0);
    asm volatile("s_waitcnt vmcnt(4)" ::: "memory");
    __builtin_amdgcn_s_barrier();

    bf16x8 af[4], bfr[4];
    for (int u = 0; u < nt; ++u) {
        const int p = u & 1;
        #pragma unroll
        for (int ph = 0; ph < 4; ++ph) {
            const int kh = ph >> 1, mh = ph & 1;
            const int slab = p * 16384 + kh * 8192;
            if (mh == 0) {
                #pragma unroll
                for (int j = 0; j < 4; j++)
                    bfr[j] = *(const bf16x8*)(lds + 32768 + slab + bofs[j]);
            }
            #pragma unroll
            for (int i = 0; i < 4; i++)
                af[i] = *(const bf16x8*)(lds + slab + aofs[mh * 4 + i]);
            if (ph == 0)      { if (u + 1 < nt) STAGE_A(u + 1, 1); }
            else if (ph == 1) { if (u + 1 < nt) STAGE_B(u + 1, 1); }
            else if (ph == 2) { if (u + 2 < nt) STAGE_A(u + 2, 0); }
            else              { if (u + 2 < nt) STAGE_B(u + 2, 0); }
            __builtin_amdgcn_s_barrier();
            asm volatile("s_waitcnt lgkmcnt(0)" ::: "memory");
            __builtin_amdgcn_sched_barrier(0);
            __builtin_amdgcn_s_setprio(1);
            #pragma unroll
            for (int i = 0; i < 4; i++)
                #pragma unroll
                for (int j = 0; j < 4; j++) {
                    if (SWAP)
                        acc[mh * 4 + i][j] = __builtin_amdgcn_mfma_f32_16x16x32_bf16(
                            bfr[j], af[i], acc[mh * 4 + i][j], 0, 0, 0);
                    else
                        acc[mh * 4 + i][j] = __builtin_amdgcn_mfma_f32_16x16x32_bf16(
                            af[i], bfr[j], acc[mh * 4 + i][j], 0, 0, 0);
                }
            __builtin_amdgcn_s_setprio(0);
            if (ph < 3) {
                __builtin_amdgcn_s_barrier();
            } else if (u < nt - 2) {
                asm volatile("s_waitcnt vmcnt(4)" ::: "memory");
                __builtin_amdgcn_s_barrier();
            } else if (u == nt - 2) {
                asm volatile("s_waitcnt vmcnt(0)" ::: "memory");
                __builtin_amdgcn_s_barrier();
            }
        }
    }
#undef STAGE_A
#undef STAGE_B
}

#define GEMM256_PROLOGUE                                              \
    __shared__ __align__(16) unsigned short lds[65536];               \
    const int b = blockIdx.z;                                         \
    const int m0 = blockIdx.y * 256, n0 = blockIdx.x * 256;           \
    const int lane = threadIdx.x & 63, wave = threadIdx.x >> 6;       \
    const int wm = wave >> 2, wn = wave & 3;                          \
    const int lrow = lane & 15, lq = lane >> 4;                       \
    floatx4 acc[8][4];                                                \
    _Pragma("unroll") for (int i = 0; i < 8; i++)                     \
        _Pragma("unroll") for (int j = 0; j < 4; j++)                 \
            acc[i][j] = (floatx4){0.f, 0.f, 0.f, 0.f};

// ---------------- QKV projection ----------------
__global__ __launch_bounds__(512, 2) void qkv_mfma(const unsigned short* __restrict__ wbf,
                                                   const unsigned short* __restrict__ xnt,
                                                   const float* __restrict__ bias,
                                                   unsigned short* __restrict__ Qb,
                                                   unsigned short* __restrict__ Kb,
                                                   unsigned short* __restrict__ Vb) {
    GEMM256_PROLOGUE
    const unsigned short* Bg = xnt + (size_t)b * (S_ * C_);
    if (m0 < 1024) {
        mfma256_loop<false>(wbf, C_, Bg, C_, 8, m0, n0, lds, acc);
        unsigned short* dst = (m0 < 512 ? Qb : Kb) + (size_t)b * (S_ * C_);
        const int osec = (m0 < 512) ? 0 : 512;
        const float sc = (m0 < 512) ? 1.f : SCALE_;
        #pragma unroll
        for (int i = 0; i < 8; i++)
            #pragma unroll
            for (int j = 0; j < 4; j++) {
                int oabs = m0 + wm * 128 + i * 16 + lq * 4;
                int s    = n0 + wn * 64 + j * 16 + lrow;
                float4 bi = *(const float4*)(bias + oabs);
                floatx4 v = acc[i][j];
                ushort4 o4;
                o4.x = f2bf((v[0] + bi.x) * sc); o4.y = f2bf((v[1] + bi.y) * sc);
                o4.z = f2bf((v[2] + bi.z) * sc); o4.w = f2bf((v[3] + bi.w) * sc);
                *(ushort4*)(dst + (size_t)s * C_ + (oabs - osec)) = o4;
            }
    } else {
        mfma256_loop<true>(wbf, C_, Bg, C_, 8, m0, n0, lds, acc);
        unsigned short* dst = Vb + (size_t)b * (C_ * S_);
        #pragma unroll
        for (int i = 0; i < 8; i++)
            #pragma unroll
            for (int j = 0; j < 4; j++) {
                int c  = m0 - 1024 + wm * 128 + i * 16 + lrow;
                int sb = n0 + wn * 64 + j * 16 + lq * 4;
                float bi = bias[1024 + c];
                floatx4 v = acc[i][j];
                ushort4 o4;
                o4.x = f2bf(v[0] + bi); o4.y = f2bf(v[1] + bi);
                o4.z = f2bf(v[2] + bi); o4.w = f2bf(v[3] + bi);
                *(ushort4*)(dst + (size_t)c * S_ + sb) = o4;
            }
    }
}

// ================= fused flash attention: scores + online softmax + PV =================
// One block per (batch, 128-row q-tile): grid 256 = 1 block/CU (XCD-swizzled).
// KV-tiles of 128; K read [s][c], V read [c][s] (both k-contiguous for their mfma role).
// S^T layout via SWAP-mfma (q on lane&15, kv on lq*4+reg) -> in-register row ownership.
// P kept in LDS [128 q][128 kv] bf16, slot^(q&7) swizzle. O acc in regs (128 VGPR),
// rescaled by f=exp(m_old-m_new) per tile, normalized by 1/l at the end.
// LDS: STG [0,64K): scores ring Kc 3x8K @0 / Qc 3x8K @24K ; PV Vc 2x32K @0 (aliased)
//      P   [64K,96K) ; RED floats @ [96K..): red_m[4][128], red_s[4][128],
//      m_buf[128], l_buf[128], f_buf[128].
#define PF_   32768   // P offset in ushorts
#define RDF_  24576   // red offset in floats ( = byte 98304 / 4 )
__global__ __launch_bounds__(512, 2) void flash_attn(const unsigned short* __restrict__ Qb,
                                                     const unsigned short* __restrict__ Kb,
                                                     const unsigned short* __restrict__ Vb,
                                                     unsigned short* __restrict__ Ob) {
    __shared__ __align__(16) unsigned short lds[51968];   // 103936 B
    float* redf = (float*)lds;                            // indices >= RDF_ only

    const int id   = blockIdx.x;
    const int xcd  = id & 7, slot = id >> 3;
    const int b    = xcd * 4 + (slot >> 3);
    const int q0   = (slot & 7) * 128;

    const int tid  = threadIdx.x;
    const int lane = tid & 63, wave = tid >> 6;
    const int wq = wave >> 2, wk = wave & 3;      // wk doubles as wc (c-quarter) in PV
    const int lrow = lane & 15, lq = lane >> 4;
    const int cs = lq ^ ((lrow >> 1) & 3);

    const unsigned short* Qg = Qb + (size_t)b * (S_ * C_);
    const unsigned short* Kg = Kb + (size_t)b * (S_ * C_);
    const unsigned short* Vg = Vb + (size_t)b * (C_ * S_);

    // per-thread staging pointers (pre-swizzled global source, linear LDS dest)
    const int scs = (tid & 3) ^ ((tid >> 3) & 3);
    const unsigned short* gq = Qg + (size_t)(q0 + (tid >> 2)) * C_ + scs * 8;
    const unsigned short* gkb = Kg + (size_t)(tid >> 2) * C_ + scs * 8;   // + kv0*C_ per tile
    const unsigned short* gvb = Vg + (size_t)(tid >> 2) * S_ + scs * 8;   // + kv0 per tile
    unsigned short* stgw = lds + wave * 512;

    // frag read offsets (ushort units)
    int kof[2], qof[4], vof[8];
    #pragma unroll
    for (int j = 0; j < 2; j++) kof[j] = (wk * 32 + j * 16 + lrow) * 32 + cs * 8;
    #pragma unroll
    for (int i = 0; i < 4; i++) qof[i] = (wq * 64 + i * 16 + lrow) * 32 + cs * 8;
    #pragma unroll
    for (int c = 0; c < 8; c++) vof[c] = (wk * 128 + c * 16 + lrow) * 32 + cs * 8;

    floatx4 acc_o[8][4];
    #pragma unroll
    for (int c = 0; c < 8; c++)
        #pragma unroll
        for (int q = 0; q < 4; q++) acc_o[c][q] = (floatx4){0.f, 0.f, 0.f, 0.f};

    if (tid < 128) { redf[RDF_ + 1024 + tid] = -3.0e38f; redf[RDF_ + 1152 + tid] = 0.f; }
    __syncthreads();

    for (int t = 0; t < 8; ++t) {
        const int kv0 = t * 128;
        const unsigned short* gk = gkb + (size_t)kv0 * C_;
        const unsigned short* gv = gvb + kv0;

        // ---- scores: S^T[kv 128][q 128] = K . Q^T over K=512, ring-3 slabs ----
        floatx4 acc_s[2][4];
        #pragma unroll
        for (int j = 0; j < 2; j++)
            #pragma unroll
            for (int i = 0; i < 4; i++) acc_s[j][i] = (floatx4){0.f, 0.f, 0.f, 0.f};

        gl16(gk,      stgw);                     // K slot0
        gl16(gq,      stgw + 12288);             // Q slot0
        gl16(gk + 32, stgw + 4096);              // K slot1
        gl16(gq + 32, stgw + 12288 + 4096);      // Q slot1
        asm volatile("s_waitcnt vmcnt(2)" ::: "memory");
        __builtin_amdgcn_s_barrier();

        #pragma unroll
        for (int ks = 0; ks < 16; ++ks) {
            const int sb = (ks % 3) * 4096;
            bf16x8 ak[2], bq[4];
            #pragma unroll
            for (int j = 0; j < 2; j++) ak[j] = *(const bf16x8*)(lds + sb + kof[j]);
            #pragma unroll
            for (int i = 0; i < 4; i++) bq[i] = *(const bf16x8*)(lds + 12288 + sb + qof[i]);
            if (ks + 2 < 16) {
                const int sn = ((ks + 2) % 3) * 4096;
                gl16(gk + (ks + 2) * 32, stgw + sn);
                gl16(gq + (ks + 2) * 32, stgw + 12288 + sn);
            }
            __builtin_amdgcn_s_setprio(1);
            #pragma unroll
            for (int j = 0; j < 2; j++)
                #pragma unroll
                for (int i = 0; i < 4; i++)
                    acc_s[j][i] = __builtin_amdgcn_mfma_f32_16x16x32_bf16(
                        ak[j], bq[i], acc_s[j][i], 0, 0, 0);
            __builtin_amdgcn_s_setprio(0);
            if (ks < 14) asm volatile("s_waitcnt vmcnt(2)" ::: "memory");
            else         asm volatile("s_waitcnt vmcnt(0)" ::: "memory");
            __builtin_amdgcn_s_barrier();
        }

        // ---- online softmax ----
        // local max over this wave's kv (jf frags x 4 regs), then over lq groups
        float tmx[4];
        #pragma unroll
        for (int i = 0; i < 4; i++) {
            floatx4 s0 = acc_s[0][i], s1 = acc_s[1][i];
            float m = fmaxf(fmaxf(fmaxf(s0[0], s0[1]), fmaxf(s0[2], s0[3])),
                            fmaxf(fmaxf(s1[0], s1[1]), fmaxf(s1[2], s1[3])));
            m = fmaxf(m, __shfl_xor(m, 16));
            m = fmaxf(m, __shfl_xor(m, 32));
            tmx[i] = m;
        }
        if (lane < 16) {
            #pragma unroll
            for (int i = 0; i < 4; i++)
                redf[RDF_ + wk * 128 + wq * 64 + i * 16 + lrow] = tmx[i];
        }
        // early-stage PV V slab0 (scores slabs dead after loop barrier)
        #pragma unroll
        for (int g = 0; g < 4; g++)
            gl16(gv + (size_t)g * (128 * S_), stgw + g * 4096);
        __syncthreads();   // A: red_m published

        float fst[4];
        if (wk == 0 && lane < 16) {
            #pragma unroll
            for (int i = 0; i < 4; i++) {
                int q = wq * 64 + i * 16 + lrow;
                float tm = fmaxf(fmaxf(redf[RDF_ + q], redf[RDF_ + 128 + q]),
                                 fmaxf(redf[RDF_ + 256 + q], redf[RDF_ + 384 + q]));
                float mo = redf[RDF_ + 1024 + q];
                float mn = fmaxf(mo, tm);
                float f  = __expf(mo - mn);
                redf[RDF_ + 1024 + q] = mn;
                redf[RDF_ + 1280 + q] = f;
                fst[i] = f;
            }
        }
        __syncthreads();   // B: m_buf/f_buf published

        float ls[4] = {0.f, 0.f, 0.f, 0.f};
        #pragma unroll
        for (int i = 0; i < 4; i++) {
            int q = wq * 64 + i * 16 + lrow;
            float mn = redf[RDF_ + 1024 + q];
            #pragma unroll
            for (int j = 0; j < 2; j++) {
                floatx4 s = acc_s[j][i];
                float p0 = __expf(s[0] - mn), p1 = __expf(s[1] - mn);
                float p2 = __expf(s[2] - mn), p3 = __expf(s[3] - mn);
                ls[i] += (p0 + p1) + (p2 + p3);
                ushort4 o; o.x = f2bf(p0); o.y = f2bf(p1); o.z = f2bf(p2); o.w = f2bf(p3);
                int kvloc = wk * 32 + j * 16 + lq * 4;
                int phys  = (kvloc >> 3) ^ (q & 7);
                *(ushort4*)(lds + PF_ + q * 128 + phys * 8 + (lq & 1) * 4) = o;
            }
            ls[i] += __shfl_xor(ls[i], 16);
            ls[i] += __shfl_xor(ls[i], 32);
        }
        if (lane < 16) {
            #pragma unroll
            for (int i = 0; i < 4; i++)
                redf[RDF_ + 512 + wk * 128 + wq * 64 + i * 16 + lrow] = ls[i];
        }
        asm volatile("s_waitcnt vmcnt(0)" ::: "memory");   // V slab0 landed
        __syncthreads();   // C: P, red_s, Vc0 published

        if (wk == 0 && lane < 16) {
            #pragma unroll
            for (int i = 0; i < 4; i++) {
                int q = wq * 64 + i * 16 + lrow;
                float ts = (redf[RDF_ + 512 + q] + redf[RDF_ + 640 + q]) +
                           (redf[RDF_ + 768 + q] + redf[RDF_ + 896 + q]);
                redf[RDF_ + 1152 + q] = redf[RDF_ + 1152 + q] * fst[i] + ts;
            }
        }
        // rescale O by f (q on lrow dim in PV layout)
        {
            float fq[4];
            #pragma unroll
            for (int qf = 0; qf < 4; qf++)
                fq[qf] = redf[RDF_ + 1280 + wq * 64 + qf * 16 + lrow];
            #pragma unroll
            for (int c = 0; c < 8; c++)
                #pragma unroll
                for (int qf = 0; qf < 4; qf++) {
                    floatx4 v = acc_o[c][qf];
                    v[0] *= fq[qf]; v[1] *= fq[qf]; v[2] *= fq[qf]; v[3] *= fq[qf];
                    acc_o[c][qf] = v;
                }
        }

        // ---- PV: O^T[c][q] += V . P^T over kv 128, ping-pong V slabs ----
        #pragma unroll
        for (int kc = 0; kc < 4; ++kc) {
            const int vb = (kc & 1) * 16384;
            bf16x8 vv[8], pv[4];
            #pragma unroll
            for (int c = 0; c < 8; c++) vv[c] = *(const bf16x8*)(lds + vb + vof[c]);
            #pragma unroll
            for (int qf = 0; qf < 4; qf++) {
                int q = wq * 64 + qf * 16 + lrow;
                int phys = ((kc * 4 + lq) ^ (q & 7));
                pv[qf] = *(const bf16x8*)(lds + PF_ + q * 128 + phys * 8);
            }
            if (kc < 3) {
                const int vn = ((kc + 1) & 1) * 16384;
                #pragma unroll
                for (int g = 0; g < 4; g++)
                    gl16(gv + (size_t)g * (128 * S_) + (kc + 1) * 32, stgw + vn + g * 4096);
            }
            __builtin_amdgcn_s_setprio(1);
            #pragma unroll
            for (int c = 0; c < 8; c++)
                #pragma unroll
                for (int qf = 0; qf < 4; qf++)
                    acc_o[c][qf] = __builtin_amdgcn_mfma_f32_16x16x32_bf16(
                        vv[c], pv[qf], acc_o[c][qf], 0, 0, 0);
            __builtin_amdgcn_s_setprio(0);
            asm volatile("s_waitcnt vmcnt(0)" ::: "memory");
            __builtin_amdgcn_s_barrier();
        }
    }

    // ---- epilogue: O = acc_o / l, store bf16 [s][c] ----
    unsigned short* op = Ob + (size_t)b * (S_ * C_);
    #pragma unroll
    for (int qf = 0; qf < 4; qf++) {
        int q = wq * 64 + qf * 16 + lrow;
        float linv = __frcp_rn(redf[RDF_ + 1152 + q]);
        #pragma unroll
        for (int c = 0; c < 8; c++) {
            int c0 = wk * 128 + c * 16 + lq * 4;
            floatx4 v = acc_o[c][qf];
            ushort4 o;
            o.x = f2bf(v[0] * linv); o.y = f2bf(v[1] * linv);
            o.z = f2bf(v[2] * linv); o.w = f2bf(v[3] * linv);
            *(ushort4*)(op + (size_t)(q0 + q) * C_ + c0) = o;
        }
    }
}

// ---------------- out projection + bias + residual ----------------
__global__ __launch_bounds__(512, 2) void out_mfma(const unsigned short* __restrict__ wbf,
                                                   const unsigned short* __restrict__ Ob,
                                                   const float* __restrict__ bias,
                                                   const float* __restrict__ x,
                                                   float* __restrict__ out) {
    GEMM256_PROLOGUE
    const unsigned short* Bg = Ob + (size_t)b * (S_ * C_);
    mfma256_loop<true>(wbf, C_, Bg, C_, 8, m0, n0, lds, acc);
    const float* xb = x + (size_t)b * (C_ * S_);
    float* ob = out + (size_t)b * (C_ * S_);
    #pragma unroll
    for (int i = 0; i < 8; i++)
        #pragma unroll
        for (int j = 0; j < 4; j++) {
            int o  = m0 + wm * 128 + i * 16 + lrow;
            int sb = n0 + wn * 64 + j * 16 + lq * 4;
            float bb = bias[o];
            size_t idx = (size_t)o * S_ + sb;
            float4 xv = *(const float4*)(xb + idx);
            floatx4 v = acc[i][j];
            float4 r;
            r.x = v[0] + bb + xv.x; r.y = v[1] + bb + xv.y;
            r.z = v[2] + bb + xv.z; r.w = v[3] + bb + xv.w;
            *(float4*)(ob + idx) = r;
        }
}

// ---------------- launch ----------------
extern "C" void kernel_launch(void* const* d_in, const int* in_sizes, int n_in,
                              void* d_out, int out_size, void* d_ws, size_t ws_size,
                              hipStream_t stream) {
    const float* x      = (const float*)d_in[0];
    const float* gamma  = (const float*)d_in[1];
    const float* beta   = (const float*)d_in[2];
    const float* w_qkv  = (const float*)d_in[3];
    const float* b_qkv  = (const float*)d_in[4];
    const float* w_out  = (const float*)d_in[5];
    const float* b_out  = (const float*)d_in[6];
    float* out          = (float*)d_out;

    char* ws = (char*)d_ws;
    // layout (bytes), aliasing is stream-order safe:
    //   Qb   [b][1024][512] bf16 @ 0       (32 MB)
    //   Kb   [b][1024][512] bf16 @ 32 MB   (32 MB)
    //   Vb   [b][512][1024] bf16 @ 64 MB   (32 MB)
    //   xnt  [b][1024][512] bf16 @ 96 MB   (32 MB)  -- dead after qkv
    //   Ob   [b][1024][512] bf16 @ 96 MB   (32 MB)  -- aliases xnt (flash reads Qb!)
    //   wqkv_bf @ 160 MB, wout_bf, stats   (~2.1 MB)
    unsigned short* Qb   = (unsigned short*)(ws);
    unsigned short* Kb   = (unsigned short*)(ws + 33554432ULL);
    unsigned short* Vb   = (unsigned short*)(ws + 67108864ULL);
    unsigned short* xnt  = (unsigned short*)(ws + 100663296ULL);
    unsigned short* Ob   = (unsigned short*)(ws + 100663296ULL);
    unsigned short* wqkv_bf = (unsigned short*)(ws + 167772160ULL);
    unsigned short* wout_bf = (unsigned short*)(ws + 167772160ULL + 1572864ULL);
    float2* stats           = (float2*)(ws + 167772160ULL + 1572864ULL + 524288ULL);

    gn_stats  <<<B_ * G_, 256, 0, stream>>>(x, stats);
    cast_bf16 <<<C3_ * C_ / 1024, 256, 0, stream>>>(w_qkv, wqkv_bf);
    cast_bf16 <<<C_ * C_ / 1024, 256, 0, stream>>>(w_out, wout_bf);
    xnt_kernel<<<dim3(16, 8, B_), 256, 0, stream>>>(x, gamma, beta, stats, xnt);
    qkv_mfma  <<<dim3(4, 6, B_), 512, 0, stream>>>(wqkv_bf, xnt, b_qkv, Qb, Kb, Vb);
    flash_attn<<<256, 512, 0, stream>>>(Qb, Kb, Vb, Ob);
    out_mfma  <<<dim3(4, 2, B_), 512, 0, stream>>>(wout_bf, Ob, b_out, x, out);
}